// Round 3
// baseline (743.541 us; speedup 1.0000x reference)
//
#include <hip/hip_runtime.h>
#include <cstdint>

// MultiHeadAttention: v[8,512,1024], mask[8,512,512](bool), w_kqs[2048,1024]+b,
// fc_w[1024,16384]+b -> out[8,512,1024], attn[16,8,512,512]  (all fp32 I/O)
// Internals bf16 MFMA. R3: depth-2 prefetch pipeline (NBUF=4, counted vmcnt,
// single fused waitcnt+barrier per K-step), FC splitK=2, PV XCD-swizzle.

typedef __attribute__((ext_vector_type(8))) short short8;
typedef __attribute__((ext_vector_type(4))) float f32x4;

__device__ __forceinline__ unsigned short f2bf(float x) {
  unsigned int u = __float_as_uint(x);
  u += 0x7FFFu + ((u >> 16) & 1u);   // RNE
  return (unsigned short)(u >> 16);
}

__device__ __forceinline__ void gld16(void* lds, const void* g) {
  __builtin_amdgcn_global_load_lds(
      (const __attribute__((address_space(1))) void*)g,
      (__attribute__((address_space(3))) void*)lds, 16, 0, 0);
}

// fused "wait for all but N oldest VMEM, then barrier" (counted vmcnt — loads
// for the next 2 tiles stay in flight across the barrier)
template<int N> __device__ __forceinline__ void wait_barrier() {
  if constexpr (N == 0)      asm volatile("s_waitcnt vmcnt(0)\n\ts_barrier" ::: "memory");
  else if constexpr (N == 3) asm volatile("s_waitcnt vmcnt(3)\n\ts_barrier" ::: "memory");
  else if constexpr (N == 4) asm volatile("s_waitcnt vmcnt(4)\n\ts_barrier" ::: "memory");
  else if constexpr (N == 6) asm volatile("s_waitcnt vmcnt(6)\n\ts_barrier" ::: "memory");
  else if constexpr (N == 8) asm volatile("s_waitcnt vmcnt(8)\n\ts_barrier" ::: "memory");
  else static_assert(N < 0, "unsupported vmcnt");
}

// ---------------------------------------------------------------------------
// bt-GEMM core, depth-2 prefetch: C = A[M,K] * B[N,K]^T, bf16, f32 acc.
// BM in {128,256}, BN=128, BK=32, THREADS=2*BM. NBUF=4 LDS buffers.
// Iter t: stage(t+2) -> s_waitcnt vmcnt(2*NLOADS) (tile t landed, t+1/t+2 in
// flight) -> s_barrier -> ds_read buf[t&3] -> MFMA.  Write-safety: buf staged
// at iter t was last read at iter t-2; barrier B_{t-1} separates.
// LDS [rows][32] linear (global_load_lds dest), 16B-granule XOR swizzle
// (chunk ^ ((row>>1)&3)) applied on SOURCE addr and on READ (same involution).
// ---------------------------------------------------------------------------
template<int BM>
__device__ __forceinline__ void gemm_bt(
    const short* __restrict__ A, int lda,
    const short* __restrict__ B, int ldb,
    int klen, short* __restrict__ ldsA, short* __restrict__ ldsB,
    f32x4 acc[4][4])
{
  constexpr int THREADS = 2 * BM;
  constexpr int NLOADS = (BM == 256) ? 3 : 4;   // gld16 per thread per stage
  constexpr int ABUF = BM * 32;                 // shorts per A buffer
  constexpr int BBUF = 128 * 32;
  const int tid = (int)threadIdx.x, lane = tid & 63, wave = tid >> 6;
  const int wr = (wave >> 1) * 64, wc = (wave & 1) * 64;
  const int fr = lane & 15, kc = lane >> 4;

  const int ra0 = tid >> 2,             ca0 = ((tid & 3) ^ ((ra0 >> 1) & 3)) << 3;
  const int a1  = tid + THREADS;
  const int ra1 = a1 >> 2,              ca1 = ((a1 & 3) ^ ((ra1 >> 1) & 3)) << 3;
  const short* pa0 = A + ra0 * lda + ca0;
  const short* pa1 = A + ra1 * lda + ca1;
  const int rb0 = tid >> 2,             cb0 = ((tid & 3) ^ ((rb0 >> 1) & 3)) << 3;
  const short* pb0 = B + (rb0 & 127) * ldb + cb0;   // THREADS=512: rb0<128 anyway
  const short* pb1 = nullptr;
  if constexpr (THREADS == 256) {
    const int b1 = tid + 256;
    const int rb1 = b1 >> 2, cb1 = ((b1 & 3) ^ ((rb1 >> 1) & 3)) << 3;
    pb1 = B + rb1 * ldb + cb1;
  }
  const int aw = wave * 512;  // wave-uniform LDS dest (shorts); HW adds lane*16B

  auto stage = [&](int buf, int k0i) {
    const int k0 = k0i << 5;
    short* dA = ldsA + buf * ABUF;
    short* dB = ldsB + buf * BBUF;
    gld16(dA + aw, pa0 + k0);
    gld16(dA + THREADS * 8 + aw, pa1 + k0);
    gld16(dB + aw, pb0 + k0);
    if constexpr (THREADS == 256) gld16(dB + 2048 + aw, pb1 + k0);
  };

  const int nt = klen >> 5;
  stage(0, 0);
  if (nt > 1) stage(1, 1);

  for (int t = 0; t < nt; ++t) {
    if (t + 2 < nt) {
      stage((t + 2) & 3, t + 2);
      wait_barrier<2 * NLOADS>();
    } else if (t + 1 < nt) {
      wait_barrier<NLOADS>();
    } else {
      wait_barrier<0>();
    }
    const short* bufA = ldsA + (t & 3) * ABUF;
    const short* bufB = ldsB + (t & 3) * BBUF;
    short8 af[4], bq[4];
#pragma unroll
    for (int m = 0; m < 4; ++m) {
      int row = wr + m * 16 + fr;
      af[m] = *(const short8*)(bufA + row * 32 + ((kc ^ ((row >> 1) & 3)) << 3));
    }
#pragma unroll
    for (int n = 0; n < 4; ++n) {
      int row = wc + n * 16 + fr;
      bq[n] = *(const short8*)(bufB + row * 32 + ((kc ^ ((row >> 1) & 3)) << 3));
    }
    __builtin_amdgcn_s_setprio(1);
#pragma unroll
    for (int m = 0; m < 4; ++m)
#pragma unroll
      for (int n = 0; n < 4; ++n)
        acc[m][n] = __builtin_amdgcn_mfma_f32_16x16x32_bf16(af[m], bq[n], acc[m][n], 0, 0, 0);
    __builtin_amdgcn_s_setprio(0);
  }
}

#define ZERO_ACC(acc)                          \
  _Pragma("unroll") for (int m = 0; m < 4; ++m) \
  _Pragma("unroll") for (int n = 0; n < 4; ++n) \
    acc[m][n] = (f32x4){0.f, 0.f, 0.f, 0.f};

// --------------------------- KQ projection ---------------------------------
__global__ __launch_bounds__(256) void proj_kernel(
    const short* __restrict__ vb, const short* __restrict__ wb,
    const float* __restrict__ bias, short* __restrict__ kqk, short* __restrict__ kqq)
{
  __shared__ short ldsA[4 * 128 * 32], ldsB[4 * 128 * 32];   // 32+32 KB
  f32x4 acc[4][4];
  ZERO_ACC(acc)
  const short* A = vb + blockIdx.y * 128 * 1024;
  const short* B = wb + blockIdx.x * 128 * 1024;
  gemm_bt<128>(A, 1024, B, 1024, 1024, ldsA, ldsB, acc);

  const int lane = threadIdx.x & 63, wave = threadIdx.x >> 6;
  const int wr = (wave >> 1) * 64, wc = (wave & 1) * 64;
  const int rg = (lane >> 4) * 4, cl = lane & 15;
#pragma unroll
  for (int m = 0; m < 4; ++m)
#pragma unroll
    for (int n = 0; n < 4; ++n)
#pragma unroll
      for (int r = 0; r < 4; ++r) {
        int row = blockIdx.y * 128 + wr + m * 16 + rg + r;   // b*512+t
        int col = blockIdx.x * 128 + wc + n * 16 + cl;       // 0..2047
        float val = acc[m][n][r] + bias[col];
        int bb = row >> 9, t = row & 511;
        int h = col >> 7, rr = col & 127;
        int base = ((h * 8 + bb) * 512 + t) * 64;
        unsigned short bv = f2bf(val);
        if (rr < 64) kqk[base + rr] = (short)bv;
        else         kqq[base + rr - 64] = (short)bv;
      }
}

// ----------------------- scores + mask + softmax ----------------------------
__global__ __launch_bounds__(256) void scores_softmax_kernel(
    const short* __restrict__ kqk, const short* __restrict__ kqq,
    const unsigned char* __restrict__ mask8, const int* __restrict__ flags,
    float* __restrict__ attn_f, short* __restrict__ attn_b)
{
  __shared__ short Kl[256 * 64];   // 32 KB
  __shared__ short Ql[64 * 64];    //  8 KB
  const int tid = threadIdx.x, lane = tid & 63, wave = tid >> 6;
  const int qt = blockIdx.x, hb = blockIdx.y, b = hb & 7;
  const int fr = lane & 15, kc = lane >> 4;
  const short* Qg = kqq + (hb * 512 + qt * 64) * 64;
  const short* Kg = kqk + hb * 512 * 64;

  f32x4 acc[32];
#pragma unroll
  for (int i = 0; i < 32; ++i) acc[i] = (f32x4){0.f, 0.f, 0.f, 0.f};

#pragma unroll
  for (int j = 0; j < 2; ++j) {
    int g = j * 256 + tid;
    int row = g >> 3, c = (g & 7) ^ (row & 7);
    gld16(Ql + (j * 256 + wave * 64) * 8, Qg + row * 64 + c * 8);
  }
  short8 aq[2];
  for (int half = 0; half < 2; ++half) {
#pragma unroll
    for (int j = 0; j < 8; ++j) {
      int g = j * 256 + tid;
      int row = g >> 3, c = (g & 7) ^ (row & 7);
      gld16(Kl + (j * 256 + wave * 64) * 8, Kg + (half * 256 + row) * 64 + c * 8);
    }
    __syncthreads();
    if (half == 0) {
      int qrow = wave * 16 + fr;
#pragma unroll
      for (int s = 0; s < 2; ++s)
        aq[s] = *(const short8*)(Ql + qrow * 64 + (((s * 4 + kc) ^ (qrow & 7)) << 3));
    }
#pragma unroll
    for (int n = 0; n < 16; ++n) {
      int krow = n * 16 + fr;
      short8 b0 = *(const short8*)(Kl + krow * 64 + ((kc ^ (krow & 7)) << 3));
      short8 b1 = *(const short8*)(Kl + krow * 64 + (((4 + kc) ^ (krow & 7)) << 3));
      acc[half * 16 + n] = __builtin_amdgcn_mfma_f32_16x16x32_bf16(aq[0], b0, acc[half * 16 + n], 0, 0, 0);
      acc[half * 16 + n] = __builtin_amdgcn_mfma_f32_16x16x32_bf16(aq[1], b1, acc[half * 16 + n], 0, 0, 0);
    }
    if (half == 0) __syncthreads();
  }

  const int f_byte = flags[0], f_f32 = flags[1];
  const int* mask32 = (const int*)mask8;
  const float* maskf = (const float*)mask8;
  const int qbase = qt * 64 + wave * 16 + (lane >> 4) * 4;

  float mrow[4] = {-3.0e38f, -3.0e38f, -3.0e38f, -3.0e38f};
#pragma unroll
  for (int n = 0; n < 32; ++n) {
    int col = n * 16 + fr;
#pragma unroll
    for (int r = 0; r < 4; ++r) {
      int midx = (b * 512 + qbase + r) * 512 + col;
      bool msk = f_byte ? (mask8[midx] != 0)
                        : (f_f32 ? (maskf[midx] != 0.0f) : (mask32[midx] != 0));
      float s = msk ? -100000.0f : acc[n][r] * 0.125f;
      acc[n][r] = s;
      mrow[r] = fmaxf(mrow[r], s);
    }
  }
#pragma unroll
  for (int r = 0; r < 4; ++r) {
    float v = mrow[r];
    v = fmaxf(v, __shfl_xor(v, 1));
    v = fmaxf(v, __shfl_xor(v, 2));
    v = fmaxf(v, __shfl_xor(v, 4));
    v = fmaxf(v, __shfl_xor(v, 8));
    mrow[r] = v;
  }
  float srow[4] = {0.f, 0.f, 0.f, 0.f};
#pragma unroll
  for (int n = 0; n < 32; ++n)
#pragma unroll
    for (int r = 0; r < 4; ++r) {
      float p = __expf(acc[n][r] - mrow[r]);
      acc[n][r] = p;
      srow[r] += p;
    }
#pragma unroll
  for (int r = 0; r < 4; ++r) {
    float v = srow[r];
    v += __shfl_xor(v, 1);
    v += __shfl_xor(v, 2);
    v += __shfl_xor(v, 4);
    v += __shfl_xor(v, 8);
    srow[r] = 1.0f / v;
  }
  const long obase = (long)hb * 512 * 512;
#pragma unroll
  for (int n = 0; n < 32; ++n) {
    int col = n * 16 + fr;
#pragma unroll
    for (int r = 0; r < 4; ++r) {
      long idx = obase + (long)(qbase + r) * 512 + col;
      float p = acc[n][r] * srow[r];
      attn_f[idx] = p;
      attn_b[idx] = (short)f2bf(p);
    }
  }
}

// ------------------------------- PV (256x128) -------------------------------
// XCD swizzle: the 16 (x,y) blocks of one z=(h,b) share A-panels + vT_b; pin
// them to one XCD. 2048 blocks: z = xcd + 8*(s>>4), inner (s&15) -> x,y.
__global__ __launch_bounds__(512) void pv_kernel(
    const short* __restrict__ attn_b, const short* __restrict__ vT,
    short* __restrict__ out_pre)
{
  __shared__ short ldsA[4 * 256 * 32], ldsB[4 * 128 * 32];   // 64+32 KB
  f32x4 acc[4][4];
  ZERO_ACC(acc)
  const int L = blockIdx.x;
  const int xcd = L & 7, s = L >> 3;
  const int z = xcd + 8 * (s >> 4);
  const int inner = s & 15, x = inner & 7, y = inner >> 3;
  const int h = z >> 3, b = z & 7;
  const short* A = attn_b + ((long)z * 512 + y * 256) * 512;
  const short* B = vT + (b * 1024 + x * 128) * 512;
  gemm_bt<256>(A, 512, B, 512, 512, ldsA, ldsB, acc);

  const int lane = threadIdx.x & 63, wave = threadIdx.x >> 6;
  const int wr = (wave >> 1) * 64, wc = (wave & 1) * 64;
  const int rg = (lane >> 4) * 4, cl = lane & 15;
#pragma unroll
  for (int m = 0; m < 4; ++m)
#pragma unroll
    for (int n = 0; n < 4; ++n)
#pragma unroll
      for (int r = 0; r < 4; ++r) {
        int q = y * 256 + wr + m * 16 + rg + r;
        int c = x * 128 + wc + n * 16 + cl;
        out_pre[((b * 512 + q) * 16 + h) * 1024 + c] = (short)f2bf(acc[m][n][r]);
      }
}

// --------------------------- FC (256x128, split-K=2) ------------------------
// 256 blocks = 1/CU. XCD swizzle: 8 N-tiles sharing an A-band co-located.
__global__ __launch_bounds__(512) void fc_kernel(
    const short* __restrict__ outp, const short* __restrict__ fcw,
    float* __restrict__ part)
{
  __shared__ short ldsA[4 * 256 * 32], ldsB[4 * 128 * 32];
  f32x4 acc[4][4];
  ZERO_ACC(acc)
  const int L = blockIdx.x;
  const int xcd = L & 7, s = L >> 3;          // s in 0..31
  const int x = s & 7;                        // N-tile (128 cols)
  const int band = xcd * 4 + (s >> 3);        // 32 (y,kz) bands
  const int y = band & 15, kz = band >> 4;    // y: M-tile, kz: split-K half
  const short* A = outp + (long)y * 256 * 16384 + kz * 8192;
  const short* B = fcw + (long)x * 128 * 16384 + kz * 8192;
  gemm_bt<256>(A, 16384, B, 16384, 8192, ldsA, ldsB, acc);

  float* P = part + (long)kz * 4194304;
  const int lane = threadIdx.x & 63, wave = threadIdx.x >> 6;
  const int wr = (wave >> 1) * 64, wc = (wave & 1) * 64;
  const int rg = (lane >> 4) * 4, cl = lane & 15;
#pragma unroll
  for (int m = 0; m < 4; ++m)
#pragma unroll
    for (int n = 0; n < 4; ++n)
#pragma unroll
      for (int r = 0; r < 4; ++r) {
        int row = y * 256 + wr + m * 16 + rg + r;
        int col = x * 128 + wc + n * 16 + cl;
        P[row * 1024 + col] = acc[m][n][r];
      }
}

__global__ void fc_reduce_kernel(const float* __restrict__ part,
                                 const float* __restrict__ fcb,
                                 float* __restrict__ out)
{
  int i = blockIdx.x * 256 + threadIdx.x;    // over 1048576 float4 groups
  f32x4 s = ((const f32x4*)part)[i];
  s += ((const f32x4*)(part + 4194304))[i];
  int j = (i * 4) & 1023;
  f32x4 bias = *(const f32x4*)(fcb + j);
  ((f32x4*)out)[i] = s + bias;
}

// ------------------------------- utilities ----------------------------------
__global__ void cvt_kernel(const float* __restrict__ in, short* __restrict__ out, int n8) {
  int i = blockIdx.x * 256 + threadIdx.x;
  if (i >= n8) return;
  f32x4 x0 = ((const f32x4*)in)[i * 2];
  f32x4 x1 = ((const f32x4*)in)[i * 2 + 1];
  short8 o;
  o[0] = (short)f2bf(x0[0]); o[1] = (short)f2bf(x0[1]);
  o[2] = (short)f2bf(x0[2]); o[3] = (short)f2bf(x0[3]);
  o[4] = (short)f2bf(x1[0]); o[5] = (short)f2bf(x1[1]);
  o[6] = (short)f2bf(x1[2]); o[7] = (short)f2bf(x1[3]);
  ((short8*)out)[i] = o;
}

// v[8,512,1024] f32 -> vT[8,1024,512] bf16
__global__ void transpose_kernel(const float* __restrict__ v, short* __restrict__ vT) {
  __shared__ float tile[32][33];
  int b = blockIdx.z, t0 = blockIdx.y * 32, c0 = blockIdx.x * 32;
  int tx = threadIdx.x, ty = threadIdx.y;   // 32 x 8
  const float* src = v + (b * 512 + t0) * 1024 + c0;
#pragma unroll
  for (int i = 0; i < 4; ++i)
    tile[ty + i * 8][tx] = src[(ty + i * 8) * 1024 + tx];
  __syncthreads();
  short* dst = vT + (b * 1024 + c0) * 512 + t0;
#pragma unroll
  for (int i = 0; i < 4; ++i)
    dst[(ty + i * 8) * 512 + tx] = (short)f2bf(tile[tx][ty + i * 8]);
}

__global__ void detect_kernel(const unsigned int* __restrict__ m, int nwords, int* flags) {
  int i = blockIdx.x * 256 + threadIdx.x;
  unsigned int f0 = 0, f1 = 0;
  for (int idx = i; idx < nwords; idx += gridDim.x * 256) {
    unsigned int u = m[idx];
    f0 |= (u >> 8) & 0xFFu;
    f1 |= u & 0xFFFF0000u;
  }
  int b0 = __any(f0 != 0), b1 = __any(f1 != 0);
  if ((threadIdx.x & 63) == 0) {
    if (b0) atomicOr(flags, 1);
    if (b1) atomicOr(flags + 1, 1);
  }
}

// ---------------------------------------------------------------------------
extern "C" void kernel_launch(void* const* d_in, const int* in_sizes, int n_in,
                              void* d_out, int out_size, void* d_ws, size_t ws_size,
                              hipStream_t stream) {
  const float* v   = (const float*)d_in[0];
  const unsigned char* mask = (const unsigned char*)d_in[1];
  const float* wkq = (const float*)d_in[2];
  const float* bkq = (const float*)d_in[3];
  const float* fcw = (const float*)d_in[4];
  const float* fcb = (const float*)d_in[5];
  float* out    = (float*)d_out;
  float* attn_f = out + 4194304;

  char* ws = (char*)d_ws;
  int*   flags = (int*)ws;
  short* vb    = (short*)(ws + 256);                  //  8 MB
  short* vt    = (short*)(ws + 8388864);              //  8 MB
  short* wkqb  = (short*)(ws + 16777472);             //  4 MB
  short* fcwb  = (short*)(ws + 20971776);             // 32 MB
  short* kqk   = (short*)(ws + 54526208);             //  8 MB
  short* kqq   = (short*)(ws + 62914816);             //  8 MB
  short* attnb = (short*)(ws + 71303424);             // 64 MB
  short* outp  = (short*)(ws + 138412288);            //128 MB
  float* part  = (float*)(ws + 71303424);             // 32 MB (aliases attnb; dead by then)

  hipMemsetAsync(d_ws, 0, 64, stream);
  detect_kernel<<<256, 256, 0, stream>>>((const unsigned int*)mask, 524288, flags);
  cvt_kernel<<<2048, 256, 0, stream>>>(v, vb, 524288);
  transpose_kernel<<<dim3(32, 16, 8), dim3(32, 8), 0, stream>>>(v, vt);
  cvt_kernel<<<1024, 256, 0, stream>>>(wkq, wkqb, 262144);
  cvt_kernel<<<8192, 256, 0, stream>>>(fcw, fcwb, 2097152);
  proj_kernel<<<dim3(16, 32), 256, 0, stream>>>(vb, wkqb, bkq, kqk, kqq);
  scores_softmax_kernel<<<dim3(8, 128), 256, 0, stream>>>(kqk, kqq, mask, flags, attn_f, attnb);
  pv_kernel<<<2048, 512, 0, stream>>>(attnb, vt, outp);
  fc_kernel<<<256, 512, 0, stream>>>(outp, fcwb, part);
  fc_reduce_kernel<<<4096, 256, 0, stream>>>(part, fcb, out);
}

// Round 4
// 663.840 us; speedup vs baseline: 1.1201x; 1.1201x over previous
//
#include <hip/hip_runtime.h>
#include <cstdint>

// MultiHeadAttention: v[8,512,1024], mask[8,512,512](bool), w_kqs[2048,1024]+b,
// fc_w[1024,16384]+b -> out[8,512,1024], attn[16,8,512,512]  (all fp32 I/O)
// Internals bf16 MFMA. R4: NBUF=3 counted-vmcnt pipeline (stage t+1, wait
// vmcnt(NLOADS) -> next tile's loads stay in flight across the barrier) at
// 72KB LDS = 2 blocks/CU for the 256-tile; FC splitK=4 (512 blocks, 2/CU).

typedef __attribute__((ext_vector_type(8))) short short8;
typedef __attribute__((ext_vector_type(4))) float f32x4;

__device__ __forceinline__ unsigned short f2bf(float x) {
  unsigned int u = __float_as_uint(x);
  u += 0x7FFFu + ((u >> 16) & 1u);   // RNE
  return (unsigned short)(u >> 16);
}

__device__ __forceinline__ void gld16(void* lds, const void* g) {
  __builtin_amdgcn_global_load_lds(
      (const __attribute__((address_space(1))) void*)g,
      (__attribute__((address_space(3))) void*)lds, 16, 0, 0);
}

// fused "wait for all but N oldest VMEM ops, then barrier" — counted vmcnt:
// the prefetched tile's loads stay in flight across the barrier.
template<int N> __device__ __forceinline__ void wait_barrier() {
  if constexpr (N == 0)      asm volatile("s_waitcnt vmcnt(0)\n\ts_barrier" ::: "memory");
  else if constexpr (N == 3) asm volatile("s_waitcnt vmcnt(3)\n\ts_barrier" ::: "memory");
  else if constexpr (N == 4) asm volatile("s_waitcnt vmcnt(4)\n\ts_barrier" ::: "memory");
  else static_assert(N < 0, "unsupported vmcnt");
}

// ---------------------------------------------------------------------------
// bt-GEMM core, counted-vmcnt prefetch, NBUF=3: C = A[M,K]*B[N,K]^T, bf16.
// BM in {128,256}, BN=128, BK=32, THREADS=2*BM.
// Iter t: stage(t+1 -> buf (t+1)%3) ; s_waitcnt vmcnt(NLOADS)  [tile t landed,
// t+1 in flight] ; s_barrier ; ds_read buf t%3 ; MFMA.
// WAR safety: buf staged at iter t was last read at iter t-2; every wave's
// t-2 ds_reads complete before it reaches the iter t-1 barrier (lgkmcnt before
// MFMA use), and the stage issues only after passing that barrier.
// Wave-own-loads: vmcnt is per-wave; each wave passes the wait only after its
// own stage-t loads landed; barrier then makes all waves' writes visible.
// LDS [rows][32] linear (global_load_lds dest), 16B-granule XOR swizzle
// (chunk ^ ((row>>1)&3)) applied on SOURCE addr and on READ (same involution).
// ---------------------------------------------------------------------------
template<int BM>
__device__ __forceinline__ void gemm_bt(
    const short* __restrict__ A, int lda,
    const short* __restrict__ B, int ldb,
    int klen, short* __restrict__ ldsA, short* __restrict__ ldsB,
    f32x4 acc[4][4])
{
  constexpr int THREADS = 2 * BM;
  constexpr int NLOADS = (BM == 256) ? 3 : 4;   // gld16 per thread per stage
  constexpr int ABUF = BM * 32;                 // shorts per A buffer
  constexpr int BBUF = 128 * 32;
  const int tid = (int)threadIdx.x, lane = tid & 63, wave = tid >> 6;
  const int wr = (wave >> 1) * 64, wc = (wave & 1) * 64;
  const int fr = lane & 15, kc = lane >> 4;

  const int ra0 = tid >> 2,             ca0 = ((tid & 3) ^ ((ra0 >> 1) & 3)) << 3;
  const int a1  = tid + THREADS;
  const int ra1 = a1 >> 2,              ca1 = ((a1 & 3) ^ ((ra1 >> 1) & 3)) << 3;
  const short* pa0 = A + ra0 * lda + ca0;
  const short* pa1 = A + ra1 * lda + ca1;
  const int rb0 = tid >> 2,             cb0 = ((tid & 3) ^ ((rb0 >> 1) & 3)) << 3;
  const short* pb0 = B + (rb0 & 127) * ldb + cb0;   // THREADS=512: rb0<128 anyway
  const short* pb1 = nullptr;
  if constexpr (THREADS == 256) {
    const int b1 = tid + 256;
    const int rb1 = b1 >> 2, cb1 = ((b1 & 3) ^ ((rb1 >> 1) & 3)) << 3;
    pb1 = B + rb1 * ldb + cb1;
  }
  const int aw = wave * 512;  // wave-uniform LDS dest (shorts); HW adds lane*16B

  auto stage = [&](int buf, int k0i) {
    const int k0 = k0i << 5;
    short* dA = ldsA + buf * ABUF;
    short* dB = ldsB + buf * BBUF;
    gld16(dA + aw, pa0 + k0);
    gld16(dA + THREADS * 8 + aw, pa1 + k0);
    gld16(dB + aw, pb0 + k0);
    if constexpr (THREADS == 256) gld16(dB + 2048 + aw, pb1 + k0);
  };

  const int nt = klen >> 5;
  stage(0, 0);

  int cur = 0;
  for (int t = 0; t < nt; ++t) {
    int nxt = cur + 1 == 3 ? 0 : cur + 1;
    if (t + 1 < nt) {
      stage(nxt, t + 1);
      wait_barrier<NLOADS>();
    } else {
      wait_barrier<0>();
    }
    const short* bufA = ldsA + cur * ABUF;
    const short* bufB = ldsB + cur * BBUF;
    short8 af[4], bq[4];
#pragma unroll
    for (int m = 0; m < 4; ++m) {
      int row = wr + m * 16 + fr;
      af[m] = *(const short8*)(bufA + row * 32 + ((kc ^ ((row >> 1) & 3)) << 3));
    }
#pragma unroll
    for (int n = 0; n < 4; ++n) {
      int row = wc + n * 16 + fr;
      bq[n] = *(const short8*)(bufB + row * 32 + ((kc ^ ((row >> 1) & 3)) << 3));
    }
    __builtin_amdgcn_s_setprio(1);
#pragma unroll
    for (int m = 0; m < 4; ++m)
#pragma unroll
      for (int n = 0; n < 4; ++n)
        acc[m][n] = __builtin_amdgcn_mfma_f32_16x16x32_bf16(af[m], bq[n], acc[m][n], 0, 0, 0);
    __builtin_amdgcn_s_setprio(0);
    cur = nxt;
  }
}

#define ZERO_ACC(acc)                          \
  _Pragma("unroll") for (int m = 0; m < 4; ++m) \
  _Pragma("unroll") for (int n = 0; n < 4; ++n) \
    acc[m][n] = (f32x4){0.f, 0.f, 0.f, 0.f};

// --------------------------- KQ projection ---------------------------------
__global__ __launch_bounds__(256, 3) void proj_kernel(
    const short* __restrict__ vb, const short* __restrict__ wb,
    const float* __restrict__ bias, short* __restrict__ kqk, short* __restrict__ kqq)
{
  __shared__ short ldsA[3 * 128 * 32], ldsB[3 * 128 * 32];   // 24+24 KB
  f32x4 acc[4][4];
  ZERO_ACC(acc)
  const short* A = vb + blockIdx.y * 128 * 1024;
  const short* B = wb + blockIdx.x * 128 * 1024;
  gemm_bt<128>(A, 1024, B, 1024, 1024, ldsA, ldsB, acc);

  const int lane = threadIdx.x & 63, wave = threadIdx.x >> 6;
  const int wr = (wave >> 1) * 64, wc = (wave & 1) * 64;
  const int rg = (lane >> 4) * 4, cl = lane & 15;
#pragma unroll
  for (int m = 0; m < 4; ++m)
#pragma unroll
    for (int n = 0; n < 4; ++n)
#pragma unroll
      for (int r = 0; r < 4; ++r) {
        int row = blockIdx.y * 128 + wr + m * 16 + rg + r;   // b*512+t
        int col = blockIdx.x * 128 + wc + n * 16 + cl;       // 0..2047
        float val = acc[m][n][r] + bias[col];
        int bb = row >> 9, t = row & 511;
        int h = col >> 7, rr = col & 127;
        int base = ((h * 8 + bb) * 512 + t) * 64;
        unsigned short bv = f2bf(val);
        if (rr < 64) kqk[base + rr] = (short)bv;
        else         kqq[base + rr - 64] = (short)bv;
      }
}

// ----------------------- scores + mask + softmax ----------------------------
__global__ __launch_bounds__(256) void scores_softmax_kernel(
    const short* __restrict__ kqk, const short* __restrict__ kqq,
    const unsigned char* __restrict__ mask8, const int* __restrict__ flags,
    float* __restrict__ attn_f, short* __restrict__ attn_b)
{
  __shared__ short Kl[256 * 64];   // 32 KB
  __shared__ short Ql[64 * 64];    //  8 KB
  const int tid = threadIdx.x, lane = tid & 63, wave = tid >> 6;
  const int qt = blockIdx.x, hb = blockIdx.y, b = hb & 7;
  const int fr = lane & 15, kc = lane >> 4;
  const short* Qg = kqq + (hb * 512 + qt * 64) * 64;
  const short* Kg = kqk + hb * 512 * 64;

  f32x4 acc[32];
#pragma unroll
  for (int i = 0; i < 32; ++i) acc[i] = (f32x4){0.f, 0.f, 0.f, 0.f};

#pragma unroll
  for (int j = 0; j < 2; ++j) {
    int g = j * 256 + tid;
    int row = g >> 3, c = (g & 7) ^ (row & 7);
    gld16(Ql + (j * 256 + wave * 64) * 8, Qg + row * 64 + c * 8);
  }
  short8 aq[2];
  for (int half = 0; half < 2; ++half) {
#pragma unroll
    for (int j = 0; j < 8; ++j) {
      int g = j * 256 + tid;
      int row = g >> 3, c = (g & 7) ^ (row & 7);
      gld16(Kl + (j * 256 + wave * 64) * 8, Kg + (half * 256 + row) * 64 + c * 8);
    }
    __syncthreads();
    if (half == 0) {
      int qrow = wave * 16 + fr;
#pragma unroll
      for (int s = 0; s < 2; ++s)
        aq[s] = *(const short8*)(Ql + qrow * 64 + (((s * 4 + kc) ^ (qrow & 7)) << 3));
    }
#pragma unroll
    for (int n = 0; n < 16; ++n) {
      int krow = n * 16 + fr;
      short8 b0 = *(const short8*)(Kl + krow * 64 + ((kc ^ (krow & 7)) << 3));
      short8 b1 = *(const short8*)(Kl + krow * 64 + (((4 + kc) ^ (krow & 7)) << 3));
      acc[half * 16 + n] = __builtin_amdgcn_mfma_f32_16x16x32_bf16(aq[0], b0, acc[half * 16 + n], 0, 0, 0);
      acc[half * 16 + n] = __builtin_amdgcn_mfma_f32_16x16x32_bf16(aq[1], b1, acc[half * 16 + n], 0, 0, 0);
    }
    if (half == 0) __syncthreads();
  }

  const int f_byte = flags[0], f_f32 = flags[1];
  const int* mask32 = (const int*)mask8;
  const float* maskf = (const float*)mask8;
  const int qbase = qt * 64 + wave * 16 + (lane >> 4) * 4;

  float mrow[4] = {-3.0e38f, -3.0e38f, -3.0e38f, -3.0e38f};
#pragma unroll
  for (int n = 0; n < 32; ++n) {
    int col = n * 16 + fr;
#pragma unroll
    for (int r = 0; r < 4; ++r) {
      int midx = (b * 512 + qbase + r) * 512 + col;
      bool msk = f_byte ? (mask8[midx] != 0)
                        : (f_f32 ? (maskf[midx] != 0.0f) : (mask32[midx] != 0));
      float s = msk ? -100000.0f : acc[n][r] * 0.125f;
      acc[n][r] = s;
      mrow[r] = fmaxf(mrow[r], s);
    }
  }
#pragma unroll
  for (int r = 0; r < 4; ++r) {
    float v = mrow[r];
    v = fmaxf(v, __shfl_xor(v, 1));
    v = fmaxf(v, __shfl_xor(v, 2));
    v = fmaxf(v, __shfl_xor(v, 4));
    v = fmaxf(v, __shfl_xor(v, 8));
    mrow[r] = v;
  }
  float srow[4] = {0.f, 0.f, 0.f, 0.f};
#pragma unroll
  for (int n = 0; n < 32; ++n)
#pragma unroll
    for (int r = 0; r < 4; ++r) {
      float p = __expf(acc[n][r] - mrow[r]);
      acc[n][r] = p;
      srow[r] += p;
    }
#pragma unroll
  for (int r = 0; r < 4; ++r) {
    float v = srow[r];
    v += __shfl_xor(v, 1);
    v += __shfl_xor(v, 2);
    v += __shfl_xor(v, 4);
    v += __shfl_xor(v, 8);
    srow[r] = 1.0f / v;
  }
  const long obase = (long)hb * 512 * 512;
#pragma unroll
  for (int n = 0; n < 32; ++n) {
    int col = n * 16 + fr;
#pragma unroll
    for (int r = 0; r < 4; ++r) {
      long idx = obase + (long)(qbase + r) * 512 + col;
      float p = acc[n][r] * srow[r];
      attn_f[idx] = p;
      attn_b[idx] = (short)f2bf(p);
    }
  }
}

// ------------------------------- PV (256x128) -------------------------------
// XCD swizzle: the 16 (x,y) blocks of one z=(h,b) share A-panels + vT_b; pin
// them to one XCD. 2048 blocks: z = xcd + 8*(s>>4), inner (s&15) -> x,y.
__global__ __launch_bounds__(512, 4) void pv_kernel(
    const short* __restrict__ attn_b, const short* __restrict__ vT,
    short* __restrict__ out_pre)
{
  __shared__ short ldsA[3 * 256 * 32], ldsB[3 * 128 * 32];   // 48+24 KB
  f32x4 acc[4][4];
  ZERO_ACC(acc)
  const int L = blockIdx.x;
  const int xcd = L & 7, s = L >> 3;
  const int z = xcd + 8 * (s >> 4);
  const int inner = s & 15, x = inner & 7, y = inner >> 3;
  const int h = z >> 3, b = z & 7;
  const short* A = attn_b + ((long)z * 512 + y * 256) * 512;
  const short* B = vT + (b * 1024 + x * 128) * 512;
  gemm_bt<256>(A, 512, B, 512, 512, ldsA, ldsB, acc);

  const int lane = threadIdx.x & 63, wave = threadIdx.x >> 6;
  const int wr = (wave >> 1) * 64, wc = (wave & 1) * 64;
  const int rg = (lane >> 4) * 4, cl = lane & 15;
#pragma unroll
  for (int m = 0; m < 4; ++m)
#pragma unroll
    for (int n = 0; n < 4; ++n)
#pragma unroll
      for (int r = 0; r < 4; ++r) {
        int q = y * 256 + wr + m * 16 + rg + r;
        int c = x * 128 + wc + n * 16 + cl;
        out_pre[((b * 512 + q) * 16 + h) * 1024 + c] = (short)f2bf(acc[m][n][r]);
      }
}

// --------------------------- FC (256x128, split-K=4) ------------------------
// 512 blocks = 2/CU. XCD swizzle: 8 N-tiles sharing an A-band co-located.
__global__ __launch_bounds__(512, 4) void fc_kernel(
    const short* __restrict__ outp, const short* __restrict__ fcw,
    float* __restrict__ part)
{
  __shared__ short ldsA[3 * 256 * 32], ldsB[3 * 128 * 32];   // 72 KB
  f32x4 acc[4][4];
  ZERO_ACC(acc)
  const int L = blockIdx.x;
  const int xcd = L & 7, s = L >> 3;
  const int x = s & 7;                      // N-tile (128 cols)
  const int band = xcd * 8 + (s >> 3);      // 64 (y,kz) bands
  const int y = band & 15, kz = band >> 4;  // y: M-tile (256 rows), kz: split-K
  const short* A = outp + (long)y * 256 * 16384 + kz * 4096;
  const short* B = fcw + (long)x * 128 * 16384 + kz * 4096;
  gemm_bt<256>(A, 16384, B, 16384, 4096, ldsA, ldsB, acc);

  float* P = part + (long)kz * 4194304;
  const int lane = threadIdx.x & 63, wave = threadIdx.x >> 6;
  const int wr = (wave >> 1) * 64, wc = (wave & 1) * 64;
  const int rg = (lane >> 4) * 4, cl = lane & 15;
#pragma unroll
  for (int m = 0; m < 4; ++m)
#pragma unroll
    for (int n = 0; n < 4; ++n)
#pragma unroll
      for (int r = 0; r < 4; ++r) {
        int row = y * 256 + wr + m * 16 + rg + r;
        int col = x * 128 + wc + n * 16 + cl;
        P[row * 1024 + col] = acc[m][n][r];
      }
}

__global__ void fc_reduce_kernel(const float* __restrict__ part,
                                 const float* __restrict__ fcb,
                                 float* __restrict__ out)
{
  int i = blockIdx.x * 256 + threadIdx.x;    // over 1048576 float4 groups
  f32x4 s = ((const f32x4*)part)[i];
  s += ((const f32x4*)(part + 4194304))[i];
  s += ((const f32x4*)(part + 2 * 4194304))[i];
  s += ((const f32x4*)(part + 3 * 4194304))[i];
  int j = (i * 4) & 1023;
  f32x4 bias = *(const f32x4*)(fcb + j);
  ((f32x4*)out)[i] = s + bias;
}

// ------------------------------- utilities ----------------------------------
__global__ void cvt_kernel(const float* __restrict__ in, short* __restrict__ out, int n8) {
  int i = blockIdx.x * 256 + threadIdx.x;
  if (i >= n8) return;
  f32x4 x0 = ((const f32x4*)in)[i * 2];
  f32x4 x1 = ((const f32x4*)in)[i * 2 + 1];
  short8 o;
  o[0] = (short)f2bf(x0[0]); o[1] = (short)f2bf(x0[1]);
  o[2] = (short)f2bf(x0[2]); o[3] = (short)f2bf(x0[3]);
  o[4] = (short)f2bf(x1[0]); o[5] = (short)f2bf(x1[1]);
  o[6] = (short)f2bf(x1[2]); o[7] = (short)f2bf(x1[3]);
  ((short8*)out)[i] = o;
}

// v[8,512,1024] f32 -> vT[8,1024,512] bf16
__global__ void transpose_kernel(const float* __restrict__ v, short* __restrict__ vT) {
  __shared__ float tile[32][33];
  int b = blockIdx.z, t0 = blockIdx.y * 32, c0 = blockIdx.x * 32;
  int tx = threadIdx.x, ty = threadIdx.y;   // 32 x 8
  const float* src = v + (b * 512 + t0) * 1024 + c0;
#pragma unroll
  for (int i = 0; i < 4; ++i)
    tile[ty + i * 8][tx] = src[(ty + i * 8) * 1024 + tx];
  __syncthreads();
  short* dst = vT + (b * 1024 + c0) * 512 + t0;
#pragma unroll
  for (int i = 0; i < 4; ++i)
    dst[(ty + i * 8) * 512 + tx] = (short)f2bf(tile[tx][ty + i * 8]);
}

__global__ void detect_kernel(const unsigned int* __restrict__ m, int nwords, int* flags) {
  int i = blockIdx.x * 256 + threadIdx.x;
  unsigned int f0 = 0, f1 = 0;
  for (int idx = i; idx < nwords; idx += gridDim.x * 256) {
    unsigned int u = m[idx];
    f0 |= (u >> 8) & 0xFFu;
    f1 |= u & 0xFFFF0000u;
  }
  int b0 = __any(f0 != 0), b1 = __any(f1 != 0);
  if ((threadIdx.x & 63) == 0) {
    if (b0) atomicOr(flags, 1);
    if (b1) atomicOr(flags + 1, 1);
  }
}

// ---------------------------------------------------------------------------
extern "C" void kernel_launch(void* const* d_in, const int* in_sizes, int n_in,
                              void* d_out, int out_size, void* d_ws, size_t ws_size,
                              hipStream_t stream) {
  const float* v   = (const float*)d_in[0];
  const unsigned char* mask = (const unsigned char*)d_in[1];
  const float* wkq = (const float*)d_in[2];
  const float* bkq = (const float*)d_in[3];
  const float* fcw = (const float*)d_in[4];
  const float* fcb = (const float*)d_in[5];
  float* out    = (float*)d_out;
  float* attn_f = out + 4194304;

  char* ws = (char*)d_ws;
  int*   flags = (int*)ws;
  short* vb    = (short*)(ws + 256);                  //  8 MB
  short* vt    = (short*)(ws + 8388864);              //  8 MB
  short* wkqb  = (short*)(ws + 16777472);             //  4 MB
  short* fcwb  = (short*)(ws + 20971776);             // 32 MB
  short* kqk   = (short*)(ws + 54526208);             //  8 MB
  short* kqq   = (short*)(ws + 62914816);             //  8 MB
  short* attnb = (short*)(ws + 71303424);             // 64 MB
  short* outp  = (short*)(ws + 138412288);            //128 MB
  float* part  = (float*)(ws + 71303424);             // 64 MB (aliases attnb; dead by then)

  hipMemsetAsync(d_ws, 0, 64, stream);
  detect_kernel<<<256, 256, 0, stream>>>((const unsigned int*)mask, 524288, flags);
  cvt_kernel<<<2048, 256, 0, stream>>>(v, vb, 524288);
  transpose_kernel<<<dim3(32, 16, 8), dim3(32, 8), 0, stream>>>(v, vt);
  cvt_kernel<<<1024, 256, 0, stream>>>(wkq, wkqb, 262144);
  cvt_kernel<<<8192, 256, 0, stream>>>(fcw, fcwb, 2097152);
  proj_kernel<<<dim3(16, 32), 256, 0, stream>>>(vb, wkqb, bkq, kqk, kqq);
  scores_softmax_kernel<<<dim3(8, 128), 256, 0, stream>>>(kqk, kqq, mask, flags, attn_f, attnb);
  pv_kernel<<<2048, 512, 0, stream>>>(attnb, vt, outp);
  fc_kernel<<<512, 512, 0, stream>>>(outp, fcwb, part);
  fc_reduce_kernel<<<4096, 256, 0, stream>>>(part, fcb, out);
}

// Round 5
// 557.370 us; speedup vs baseline: 1.3340x; 1.1910x over previous
//
#include <hip/hip_runtime.h>
#include <cstdint>

// MultiHeadAttention: v[8,512,1024], mask[8,512,512](bool), w_kqs[2048,1024]+b,
// fc_w[1024,16384]+b -> out[8,512,1024], attn[16,8,512,512]  (all fp32 I/O)
// Internals bf16 MFMA. R5: mask->bitmask preprocessing (kills 128 scalar byte
// loads/thread in scores); depth-2 prefetch pipeline (NBUF=3, counted vmcnt,
// bar1=wait+barrier / bar2=plain barrier) at 72KB LDS = 2 blocks/CU.

typedef __attribute__((ext_vector_type(8))) short short8;
typedef __attribute__((ext_vector_type(4))) float f32x4;

__device__ __forceinline__ unsigned short f2bf(float x) {
  unsigned int u = __float_as_uint(x);
  u += 0x7FFFu + ((u >> 16) & 1u);   // RNE
  return (unsigned short)(u >> 16);
}

__device__ __forceinline__ void gld16(void* lds, const void* g) {
  __builtin_amdgcn_global_load_lds(
      (const __attribute__((address_space(1))) void*)g,
      (__attribute__((address_space(3))) void*)lds, 16, 0, 0);
}

// "wait for all but N oldest VMEM ops, then barrier" — counted vmcnt: the
// prefetched tiles' loads stay in flight across the barrier.
template<int N> __device__ __forceinline__ void wait_barrier() {
  if constexpr (N == 0)      asm volatile("s_waitcnt vmcnt(0)\n\ts_barrier" ::: "memory");
  else if constexpr (N == 3) asm volatile("s_waitcnt vmcnt(3)\n\ts_barrier" ::: "memory");
  else if constexpr (N == 4) asm volatile("s_waitcnt vmcnt(4)\n\ts_barrier" ::: "memory");
  else if constexpr (N == 6) asm volatile("s_waitcnt vmcnt(6)\n\ts_barrier" ::: "memory");
  else if constexpr (N == 8) asm volatile("s_waitcnt vmcnt(8)\n\ts_barrier" ::: "memory");
  else static_assert(N < 0, "unsupported vmcnt");
}
__device__ __forceinline__ void barrier_only() {
  asm volatile("s_barrier" ::: "memory");
}

// ---------------------------------------------------------------------------
// bt-GEMM core, depth-2 prefetch, NBUF=3: C = A[M,K]*B[N,K]^T, bf16, f32 acc.
// BM in {128,256}, BN=128, BK=32, THREADS=2*BM.
// iter t: stage(t+2 -> buf (t+2)%3); s_waitcnt vmcnt(2*NLOADS) [tile t landed,
// t+1/t+2 in flight]; s_barrier (RAW: all waves' tile-t writes landed);
// ds_read buf t%3; MFMA; s_barrier (WAR: all reads of buf t%3 done before
// iter t+1 stages into it — (t+1)+2 ≡ t mod 3).
// LDS [rows][32] linear (global_load_lds dest), 16B-granule XOR swizzle
// (chunk ^ ((row>>1)&3)) applied on SOURCE addr and on READ (same involution).
// ---------------------------------------------------------------------------
template<int BM>
__device__ __forceinline__ void gemm_bt(
    const short* __restrict__ A, int lda,
    const short* __restrict__ B, int ldb,
    int klen, short* __restrict__ ldsA, short* __restrict__ ldsB,
    f32x4 acc[4][4])
{
  constexpr int THREADS = 2 * BM;
  constexpr int NLOADS = (BM == 256) ? 3 : 4;   // gld16 per thread per stage
  constexpr int ABUF = BM * 32;                 // shorts per A buffer
  constexpr int BBUF = 128 * 32;
  const int tid = (int)threadIdx.x, lane = tid & 63, wave = tid >> 6;
  const int wr = (wave >> 1) * 64, wc = (wave & 1) * 64;
  const int fr = lane & 15, kc = lane >> 4;

  const int ra0 = tid >> 2,             ca0 = ((tid & 3) ^ ((ra0 >> 1) & 3)) << 3;
  const int a1  = tid + THREADS;
  const int ra1 = a1 >> 2,              ca1 = ((a1 & 3) ^ ((ra1 >> 1) & 3)) << 3;
  const short* pa0 = A + ra0 * lda + ca0;
  const short* pa1 = A + ra1 * lda + ca1;
  const int rb0 = tid >> 2,             cb0 = ((tid & 3) ^ ((rb0 >> 1) & 3)) << 3;
  const short* pb0 = B + (rb0 & 127) * ldb + cb0;   // THREADS=512: rb0<128 anyway
  const short* pb1 = nullptr;
  if constexpr (THREADS == 256) {
    const int b1 = tid + 256;
    const int rb1 = b1 >> 2, cb1 = ((b1 & 3) ^ ((rb1 >> 1) & 3)) << 3;
    pb1 = B + rb1 * ldb + cb1;
  }
  const int aw = wave * 512;  // wave-uniform LDS dest (shorts); HW adds lane*16B

  auto stage = [&](int buf, int k0i) {
    const int k0 = k0i << 5;
    short* dA = ldsA + buf * ABUF;
    short* dB = ldsB + buf * BBUF;
    gld16(dA + aw, pa0 + k0);
    gld16(dA + THREADS * 8 + aw, pa1 + k0);
    gld16(dB + aw, pb0 + k0);
    if constexpr (THREADS == 256) gld16(dB + 2048 + aw, pb1 + k0);
  };

  const int nt = klen >> 5;
  stage(0, 0);
  if (nt > 1) stage(1, 1);

  int cur = 0;
  for (int t = 0; t < nt; ++t) {
    if (t + 2 < nt) {
      int dst = (cur >= 1) ? cur - 1 : cur + 2;   // (t+2)%3
      stage(dst, t + 2);
      wait_barrier<2 * NLOADS>();
    } else if (t + 1 < nt) {
      wait_barrier<NLOADS>();
    } else {
      wait_barrier<0>();
    }
    const short* bufA = ldsA + cur * ABUF;
    const short* bufB = ldsB + cur * BBUF;
    short8 af[4], bq[4];
#pragma unroll
    for (int m = 0; m < 4; ++m) {
      int row = wr + m * 16 + fr;
      af[m] = *(const short8*)(bufA + row * 32 + ((kc ^ ((row >> 1) & 3)) << 3));
    }
#pragma unroll
    for (int n = 0; n < 4; ++n) {
      int row = wc + n * 16 + fr;
      bq[n] = *(const short8*)(bufB + row * 32 + ((kc ^ ((row >> 1) & 3)) << 3));
    }
    __builtin_amdgcn_s_setprio(1);
#pragma unroll
    for (int m = 0; m < 4; ++m)
#pragma unroll
      for (int n = 0; n < 4; ++n)
        acc[m][n] = __builtin_amdgcn_mfma_f32_16x16x32_bf16(af[m], bq[n], acc[m][n], 0, 0, 0);
    __builtin_amdgcn_s_setprio(0);
    barrier_only();                 // WAR: reads of buf cur done before reuse
    cur = (cur >= 2) ? 0 : cur + 1;
  }
}

#define ZERO_ACC(acc)                          \
  _Pragma("unroll") for (int m = 0; m < 4; ++m) \
  _Pragma("unroll") for (int n = 0; n < 4; ++n) \
    acc[m][n] = (f32x4){0.f, 0.f, 0.f, 0.f};

// --------------------------- KQ projection ---------------------------------
__global__ __launch_bounds__(256, 3) void proj_kernel(
    const short* __restrict__ vb, const short* __restrict__ wb,
    const float* __restrict__ bias, short* __restrict__ kqk, short* __restrict__ kqq)
{
  __shared__ short ldsA[3 * 128 * 32], ldsB[3 * 128 * 32];   // 24+24 KB
  f32x4 acc[4][4];
  ZERO_ACC(acc)
  const short* A = vb + blockIdx.y * 128 * 1024;
  const short* B = wb + blockIdx.x * 128 * 1024;
  gemm_bt<128>(A, 1024, B, 1024, 1024, ldsA, ldsB, acc);

  const int lane = threadIdx.x & 63, wave = threadIdx.x >> 6;
  const int wr = (wave >> 1) * 64, wc = (wave & 1) * 64;
  const int rg = (lane >> 4) * 4, cl = lane & 15;
#pragma unroll
  for (int m = 0; m < 4; ++m)
#pragma unroll
    for (int n = 0; n < 4; ++n)
#pragma unroll
      for (int r = 0; r < 4; ++r) {
        int row = blockIdx.y * 128 + wr + m * 16 + rg + r;   // b*512+t
        int col = blockIdx.x * 128 + wc + n * 16 + cl;       // 0..2047
        float val = acc[m][n][r] + bias[col];
        int bb = row >> 9, t = row & 511;
        int h = col >> 7, rr = col & 127;
        int base = ((h * 8 + bb) * 512 + t) * 64;
        unsigned short bv = f2bf(val);
        if (rr < 64) kqk[base + rr] = (short)bv;
        else         kqq[base + rr - 64] = (short)bv;
      }
}

// ----------------------- scores + mask + softmax ----------------------------
// grid(8,128): block = 64 q-rows of one (h,b); each wave owns 16 full rows.
// Mask comes as precomputed bitmask (u64 per 64 cols), staged to LDS (4KB).
__global__ __launch_bounds__(256) void scores_softmax_kernel(
    const short* __restrict__ kqk, const short* __restrict__ kqq,
    const unsigned long long* __restrict__ mbits,
    float* __restrict__ attn_f, short* __restrict__ attn_b)
{
  __shared__ short Kl[256 * 64];               // 32 KB
  __shared__ short Ql[64 * 64];                //  8 KB
  __shared__ unsigned long long Ml[64 * 8];    //  4 KB
  const int tid = threadIdx.x, lane = tid & 63, wave = tid >> 6;
  const int qt = blockIdx.x, hb = blockIdx.y, b = hb & 7;
  const int fr = lane & 15, kc = lane >> 4;
  const short* Qg = kqq + (hb * 512 + qt * 64) * 64;
  const short* Kg = kqk + hb * 512 * 64;
  const unsigned long long* Mg = mbits + ((long)(b * 512) + qt * 64) * 8;

  f32x4 acc[32];
#pragma unroll
  for (int i = 0; i < 32; ++i) acc[i] = (f32x4){0.f, 0.f, 0.f, 0.f};

  // stage Q (rows of 64 elems = 8 granules; swizzle c ^ (row&7)) + mask bits
#pragma unroll
  for (int j = 0; j < 2; ++j) {
    int g = j * 256 + tid;
    int row = g >> 3, c = (g & 7) ^ (row & 7);
    gld16(Ql + (j * 256 + wave * 64) * 8, Qg + row * 64 + c * 8);
  }
  gld16((char*)Ml + wave * 1024, (const char*)Mg + tid * 16);  // linear 4KB

  short8 aq[2];
  for (int half = 0; half < 2; ++half) {
#pragma unroll
    for (int j = 0; j < 8; ++j) {
      int g = j * 256 + tid;
      int row = g >> 3, c = (g & 7) ^ (row & 7);
      gld16(Kl + (j * 256 + wave * 64) * 8, Kg + (half * 256 + row) * 64 + c * 8);
    }
    __syncthreads();
    if (half == 0) {
      int qrow = wave * 16 + fr;
#pragma unroll
      for (int s = 0; s < 2; ++s)
        aq[s] = *(const short8*)(Ql + qrow * 64 + (((s * 4 + kc) ^ (qrow & 7)) << 3));
    }
#pragma unroll
    for (int n = 0; n < 16; ++n) {
      int krow = n * 16 + fr;
      short8 b0 = *(const short8*)(Kl + krow * 64 + ((kc ^ (krow & 7)) << 3));
      short8 b1 = *(const short8*)(Kl + krow * 64 + (((4 + kc) ^ (krow & 7)) << 3));
      acc[half * 16 + n] = __builtin_amdgcn_mfma_f32_16x16x32_bf16(aq[0], b0, acc[half * 16 + n], 0, 0, 0);
      acc[half * 16 + n] = __builtin_amdgcn_mfma_f32_16x16x32_bf16(aq[1], b1, acc[half * 16 + n], 0, 0, 0);
    }
    if (half == 0) __syncthreads();
  }

  // ---- mask (bit test from LDS) + scale + softmax over in-register rows ----
  const int lrow0 = wave * 16 + kc * 4;     // local row base for this thread
  float mrow[4], srow[4];
#pragma unroll
  for (int r = 0; r < 4; ++r) {
    const unsigned long long* mw = Ml + (lrow0 + r) * 8;
    float mx = -3.0e38f;
#pragma unroll
    for (int w = 0; w < 8; ++w) {
      unsigned long long sh = mw[w] >> fr;    // bit for n=w*4+nn at pos nn*16
      unsigned int lo = (unsigned int)sh, hi = (unsigned int)(sh >> 32);
#pragma unroll
      for (int nn = 0; nn < 4; ++nn) {
        int n = w * 4 + nn;
        unsigned int bit = ((nn < 2 ? lo : hi) >> ((nn & 1) << 4)) & 1u;
        float s = bit ? -100000.0f : acc[n][r] * 0.125f;
        acc[n][r] = s;
        mx = fmaxf(mx, s);
      }
    }
    mrow[r] = mx;
  }
#pragma unroll
  for (int r = 0; r < 4; ++r) {
    float v = mrow[r];
    v = fmaxf(v, __shfl_xor(v, 1));
    v = fmaxf(v, __shfl_xor(v, 2));
    v = fmaxf(v, __shfl_xor(v, 4));
    v = fmaxf(v, __shfl_xor(v, 8));
    mrow[r] = v;
  }
#pragma unroll
  for (int r = 0; r < 4; ++r) {
    float s0 = 0.f, s1 = 0.f;                 // split accumulators (dep chain)
#pragma unroll
    for (int n = 0; n < 32; n += 2) {
      float p0 = __expf(acc[n][r] - mrow[r]);
      float p1 = __expf(acc[n + 1][r] - mrow[r]);
      acc[n][r] = p0; acc[n + 1][r] = p1;
      s0 += p0; s1 += p1;
    }
    srow[r] = s0 + s1;
  }
#pragma unroll
  for (int r = 0; r < 4; ++r) {
    float v = srow[r];
    v += __shfl_xor(v, 1);
    v += __shfl_xor(v, 2);
    v += __shfl_xor(v, 4);
    v += __shfl_xor(v, 8);
    srow[r] = 1.0f / v;
  }
  const int qbase = qt * 64 + lrow0;
  const long obase = (long)hb * 512 * 512;
#pragma unroll
  for (int n = 0; n < 32; ++n) {
    int col = n * 16 + fr;
#pragma unroll
    for (int r = 0; r < 4; ++r) {
      long idx = obase + (long)(qbase + r) * 512 + col;
      float p = acc[n][r] * srow[r];
      attn_f[idx] = p;
      attn_b[idx] = (short)f2bf(p);
    }
  }
}

// ------------------------------- PV (256x128) -------------------------------
// XCD swizzle: the 16 (x,y) blocks of one z=(h,b) share A-panels + vT_b.
__global__ __launch_bounds__(512, 4) void pv_kernel(
    const short* __restrict__ attn_b, const short* __restrict__ vT,
    short* __restrict__ out_pre)
{
  __shared__ short ldsA[3 * 256 * 32], ldsB[3 * 128 * 32];   // 48+24 KB
  f32x4 acc[4][4];
  ZERO_ACC(acc)
  const int L = blockIdx.x;
  const int xcd = L & 7, s = L >> 3;
  const int z = xcd + 8 * (s >> 4);
  const int inner = s & 15, x = inner & 7, y = inner >> 3;
  const int h = z >> 3, b = z & 7;
  const short* A = attn_b + ((long)z * 512 + y * 256) * 512;
  const short* B = vT + (b * 1024 + x * 128) * 512;
  gemm_bt<256>(A, 512, B, 512, 512, ldsA, ldsB, acc);

  const int lane = threadIdx.x & 63, wave = threadIdx.x >> 6;
  const int wr = (wave >> 1) * 64, wc = (wave & 1) * 64;
  const int rg = (lane >> 4) * 4, cl = lane & 15;
#pragma unroll
  for (int m = 0; m < 4; ++m)
#pragma unroll
    for (int n = 0; n < 4; ++n)
#pragma unroll
      for (int r = 0; r < 4; ++r) {
        int q = y * 256 + wr + m * 16 + rg + r;
        int c = x * 128 + wc + n * 16 + cl;
        out_pre[((b * 512 + q) * 16 + h) * 1024 + c] = (short)f2bf(acc[m][n][r]);
      }
}

// --------------------------- FC (256x128, split-K=4) ------------------------
// 512 blocks = 2/CU. XCD swizzle: 8 N-tiles sharing an A-band co-located.
__global__ __launch_bounds__(512, 4) void fc_kernel(
    const short* __restrict__ outp, const short* __restrict__ fcw,
    float* __restrict__ part)
{
  __shared__ short ldsA[3 * 256 * 32], ldsB[3 * 128 * 32];   // 72 KB
  f32x4 acc[4][4];
  ZERO_ACC(acc)
  const int L = blockIdx.x;
  const int xcd = L & 7, s = L >> 3;
  const int x = s & 7;                      // N-tile (128 cols)
  const int band = xcd * 8 + (s >> 3);      // 64 (y,kz) bands
  const int y = band & 15, kz = band >> 4;  // y: M-tile (256 rows), kz: split-K
  const short* A = outp + (long)y * 256 * 16384 + kz * 4096;
  const short* B = fcw + (long)x * 128 * 16384 + kz * 4096;
  gemm_bt<256>(A, 16384, B, 16384, 4096, ldsA, ldsB, acc);

  float* P = part + (long)kz * 4194304;
  const int lane = threadIdx.x & 63, wave = threadIdx.x >> 6;
  const int wr = (wave >> 1) * 64, wc = (wave & 1) * 64;
  const int rg = (lane >> 4) * 4, cl = lane & 15;
#pragma unroll
  for (int m = 0; m < 4; ++m)
#pragma unroll
    for (int n = 0; n < 4; ++n)
#pragma unroll
      for (int r = 0; r < 4; ++r) {
        int row = y * 256 + wr + m * 16 + rg + r;
        int col = x * 128 + wc + n * 16 + cl;
        P[row * 1024 + col] = acc[m][n][r];
      }
}

__global__ void fc_reduce_kernel(const float* __restrict__ part,
                                 const float* __restrict__ fcb,
                                 float* __restrict__ out)
{
  int i = blockIdx.x * 256 + threadIdx.x;    // over 1048576 float4 groups
  f32x4 s = ((const f32x4*)part)[i];
  s += ((const f32x4*)(part + 4194304))[i];
  s += ((const f32x4*)(part + 2 * 4194304))[i];
  s += ((const f32x4*)(part + 3 * 4194304))[i];
  int j = (i * 4) & 1023;
  f32x4 bias = *(const f32x4*)(fcb + j);
  ((f32x4*)out)[i] = s + bias;
}

// ------------------------------- utilities ----------------------------------
__global__ void cvt_kernel(const float* __restrict__ in, short* __restrict__ out, int n8) {
  int i = blockIdx.x * 256 + threadIdx.x;
  if (i >= n8) return;
  f32x4 x0 = ((const f32x4*)in)[i * 2];
  f32x4 x1 = ((const f32x4*)in)[i * 2 + 1];
  short8 o;
  o[0] = (short)f2bf(x0[0]); o[1] = (short)f2bf(x0[1]);
  o[2] = (short)f2bf(x0[2]); o[3] = (short)f2bf(x0[3]);
  o[4] = (short)f2bf(x1[0]); o[5] = (short)f2bf(x1[1]);
  o[6] = (short)f2bf(x1[2]); o[7] = (short)f2bf(x1[3]);
  ((short8*)out)[i] = o;
}

// v[8,512,1024] f32 -> vT[8,1024,512] bf16
__global__ void transpose_kernel(const float* __restrict__ v, short* __restrict__ vT) {
  __shared__ float tile[32][33];
  int b = blockIdx.z, t0 = blockIdx.y * 32, c0 = blockIdx.x * 32;
  int tx = threadIdx.x, ty = threadIdx.y;   // 32 x 8
  const float* src = v + (b * 512 + t0) * 1024 + c0;
#pragma unroll
  for (int i = 0; i < 4; ++i)
    tile[ty + i * 8][tx] = src[(ty + i * 8) * 1024 + tx];
  __syncthreads();
  short* dst = vT + (b * 1024 + c0) * 512 + t0;
#pragma unroll
  for (int i = 0; i < 4; ++i)
    dst[(ty + i * 8) * 512 + tx] = (short)f2bf(tile[tx][ty + i * 8]);
}

// mask layout detector: bytes at idx%4==1 nonzero -> int8/bool layout;
// else bytes at %4 in {2,3} nonzero -> f32 layout; else int32 layout.
__global__ void detect_kernel(const unsigned int* __restrict__ m, int nwords, int* flags) {
  int i = blockIdx.x * 256 + threadIdx.x;
  unsigned int f0 = 0, f1 = 0;
  for (int idx = i; idx < nwords; idx += gridDim.x * 256) {
    unsigned int u = m[idx];
    f0 |= (u >> 8) & 0xFFu;
    f1 |= u & 0xFFFF0000u;
  }
  int b0 = __any(f0 != 0), b1 = __any(f1 != 0);
  if ((threadIdx.x & 63) == 0) {
    if (b0) atomicOr(flags, 1);
    if (b1) atomicOr(flags + 1, 1);
  }
}

// mask[8,512,512] -> bitmask: mbits[row*8+w] bit j = mask[row][w*64+j] != 0.
// One wave per output u64 (64 coalesced lane reads + __ballot).
__global__ void maskbits_kernel(const unsigned char* __restrict__ mask8,
                                const int* __restrict__ flags,
                                unsigned long long* __restrict__ mbits) {
  int word = blockIdx.x * 4 + (threadIdx.x >> 6);   // 32768 words
  int lane = threadIdx.x & 63;
  long e = (long)(word >> 3) * 512 + (word & 7) * 64 + lane;
  const int f_byte = flags[0], f_f32 = flags[1];
  bool nz;
  if (f_byte)      nz = mask8[e] != 0;
  else if (f_f32)  nz = ((const float*)mask8)[e] != 0.0f;
  else             nz = ((const int*)mask8)[e] != 0;
  unsigned long long bl = __ballot(nz);
  if (lane == 0) mbits[word] = bl;
}

// ---------------------------------------------------------------------------
extern "C" void kernel_launch(void* const* d_in, const int* in_sizes, int n_in,
                              void* d_out, int out_size, void* d_ws, size_t ws_size,
                              hipStream_t stream) {
  const float* v   = (const float*)d_in[0];
  const unsigned char* mask = (const unsigned char*)d_in[1];
  const float* wkq = (const float*)d_in[2];
  const float* bkq = (const float*)d_in[3];
  const float* fcw = (const float*)d_in[4];
  const float* fcb = (const float*)d_in[5];
  float* out    = (float*)d_out;
  float* attn_f = out + 4194304;

  char* ws = (char*)d_ws;
  int*   flags = (int*)ws;                                 // 64 B
  unsigned long long* mbits = (unsigned long long*)(ws + 4096);   // 256 KB
  short* vb    = (short*)(ws + 270336);               //  8 MB
  short* vt    = (short*)(ws + 8658944);              //  8 MB
  short* wkqb  = (short*)(ws + 17047552);             //  4 MB
  short* fcwb  = (short*)(ws + 21241856);             // 32 MB
  short* kqk   = (short*)(ws + 54796288);             //  8 MB
  short* kqq   = (short*)(ws + 63184896);             //  8 MB
  short* attnb = (short*)(ws + 71573504);             // 64 MB
  short* outp  = (short*)(ws + 138682368);            // 128 MB
  float* part  = (float*)(ws + 71573504);             // 64 MB (aliases attnb; dead by then)

  hipMemsetAsync(d_ws, 0, 64, stream);
  detect_kernel<<<256, 256, 0, stream>>>((const unsigned int*)mask, 524288, flags);
  maskbits_kernel<<<8192, 256, 0, stream>>>(mask, flags, mbits);
  cvt_kernel<<<2048, 256, 0, stream>>>(v, vb, 524288);
  transpose_kernel<<<dim3(32, 16, 8), dim3(32, 8), 0, stream>>>(v, vt);
  cvt_kernel<<<1024, 256, 0, stream>>>(wkq, wkqb, 262144);
  cvt_kernel<<<8192, 256, 0, stream>>>(fcw, fcwb, 2097152);
  proj_kernel<<<dim3(16, 32), 256, 0, stream>>>(vb, wkqb, bkq, kqk, kqq);
  scores_softmax_kernel<<<dim3(8, 128), 256, 0, stream>>>(kqk, kqq, mbits, attn_f, attnb);
  pv_kernel<<<2048, 512, 0, stream>>>(attnb, vt, outp);
  fc_kernel<<<512, 512, 0, stream>>>(outp, fcwb, part);
  fc_reduce_kernel<<<4096, 256, 0, stream>>>(part, fcb, out);
}